// Round 3
// baseline (195.578 us; speedup 1.0000x reference)
//
#include <hip/hip_runtime.h>
#include <hip/hip_bf16.h>

#define DM 512
#define NTOK 1024
#define NB 16

typedef _Float16 f16;
typedef _Float16 half8 __attribute__((ext_vector_type(8)));
typedef _Float16 half4_t __attribute__((ext_vector_type(4)));
typedef float f32x4 __attribute__((ext_vector_type(4)));

__device__ __forceinline__ void gload16(const void* g, void* l) {
    __builtin_amdgcn_global_load_lds(
        (const __attribute__((address_space(1))) void*)g,
        (__attribute__((address_space(3))) void*)l, 16, 0, 0);
}

// ---------------- transpose + convert: x f32 [B][C][N] -> xt f16 [B][N][C] ----------------
__global__ __launch_bounds__(256)
void transpose_x_kernel(const float* __restrict__ x, f16* __restrict__ xt) {
    __shared__ float tile[32][33];
    int b = blockIdx.z;
    int n0 = blockIdx.x * 32, c0 = blockIdx.y * 32;
    int tx = threadIdx.x, ty = threadIdx.y;  // 32 x 8
    const float* xb = x + (size_t)b * DM * NTOK;
#pragma unroll
    for (int i = 0; i < 32; i += 8)
        tile[ty + i][tx] = xb[(size_t)(c0 + ty + i) * NTOK + n0 + tx];
    __syncthreads();
    f16* xtb = xt + (size_t)b * NTOK * DM;
#pragma unroll
    for (int i = 0; i < 32; i += 8)
        xtb[(size_t)(n0 + ty + i) * DM + c0 + tx] = (f16)tile[tx][ty + i];
}

// concat-convert Wq,Wk,Wv -> wqkvh [1536][512] f16, plus bias concat -> bqkv f32[1536]
__global__ __launch_bounds__(256)
void convert_wqkv_kernel(const float* __restrict__ Wq, const float* __restrict__ Wk,
                         const float* __restrict__ Wv, const float* __restrict__ bq,
                         const float* __restrict__ bk, const float* __restrict__ bv,
                         f16* __restrict__ dst, float* __restrict__ bdst) {
    int i = blockIdx.x * 256 + threadIdx.x;  // 0..786431
    int row = i >> 9, col = i & 511;
    float v = (row < 512) ? Wq[i] : (row < 1024) ? Wk[(row - 512) * 512 + col]
                                                 : Wv[(row - 1024) * 512 + col];
    dst[i] = (f16)v;
    if (i < 1536)
        bdst[i] = (i < 512) ? bq[i] : (i < 1024) ? bk[i - 512] : bv[i - 1024];
}

__global__ __launch_bounds__(256)
void convert_w_kernel(const float* __restrict__ src, f16* __restrict__ dst, int n) {
    int i = blockIdx.x * 256 + threadIdx.x;
    if (i < n) dst[i] = (f16)src[i];
}

// ---------------- NT GEMM: D[i][j] = sum_k A[i][k]*B[j][k], 128x128 tile, 4 waves ----------------
// MODE 0: QKV — gj<1024: f16 qk[z][gi][gj]=D+bias[gj]; gj>=1024: f16 aux(vh)[z][gj-1024][gi]=D+bias[gj]
// MODE 2: scores — e=exp(min(D*scale,14)-4), f16 into e-slot (row-interleaved in attn f32 rows),
//         plus rowsum atomics (16-lane shuffle reduce first)
// MODE 3: f32 out = D + bias[gi] + resid
// MODE 5: PV — f16 out = D * (1/rowsum[gi])
template<int MODE, int KC>
__global__ __launch_bounds__(256)
void gemm_nt(const f16* __restrict__ A, const f16* __restrict__ B, void* __restrict__ Cout,
             const float* __restrict__ bias, const float* __restrict__ resid,
             f16* __restrict__ aux, float* __restrict__ rowsum,
             int ldA, int ldB, int ldC,
             long sA, long sB, long sC, long sR, float scale) {
    __shared__ f16 As[128 * 32];
    __shared__ f16 Bs[128 * 32];
    int z = blockIdx.z;
    const f16* Ab = A + (size_t)z * sA;
    const f16* Bb = B + (size_t)z * sB;
    int tid = threadIdx.x;
    int wave = tid >> 6, lane = tid & 63;
    int wr = wave >> 1, wc = wave & 1;
    int tI = blockIdx.y * 128, tJ = blockIdx.x * 128;

    f32x4 acc[4][4];
#pragma unroll
    for (int m = 0; m < 4; ++m)
#pragma unroll
        for (int n = 0; n < 4; ++n) acc[m][n] = (f32x4){0.f, 0.f, 0.f, 0.f};

    int frow = lane & 15, fk = (lane >> 4) * 8;   // fragment addressing
    int sr = lane >> 2, sc = (lane & 3) * 8;      // staging addressing

    for (int k0 = 0; k0 < KC; k0 += 32) {
#pragma unroll
        for (int h = 0; h < 2; ++h) {
            int chunk = wave * 2 + h;             // 0..7, 16 rows each
            int r = chunk * 16 + sr;
            const f16* ga = Ab + (size_t)(tI + r) * ldA + k0 + sc;
            const f16* gb = Bb + (size_t)(tJ + r) * ldB + k0 + sc;
            gload16(ga, &As[chunk * 512 + lane * 8]);
            gload16(gb, &Bs[chunk * 512 + lane * 8]);
        }
        asm volatile("s_waitcnt vmcnt(0)" ::: "memory");
        __syncthreads();

        half8 af[4], bf[4];
#pragma unroll
        for (int m = 0; m < 4; ++m)
            af[m] = *(const half8*)&As[(wr * 64 + m * 16 + frow) * 32 + fk];
#pragma unroll
        for (int n = 0; n < 4; ++n)
            bf[n] = *(const half8*)&Bs[(wc * 64 + n * 16 + frow) * 32 + fk];
#pragma unroll
        for (int m = 0; m < 4; ++m)
#pragma unroll
            for (int n = 0; n < 4; ++n)
                acc[m][n] = __builtin_amdgcn_mfma_f32_16x16x32_f16(af[m], bf[n], acc[m][n], 0, 0, 0);
        __syncthreads();
    }

    // epilogue: D row = (lane>>4)*4 + r, col = lane&15  (verified m89 mapping)
    int ro = (lane >> 4) * 4, co = lane & 15;
#pragma unroll
    for (int m = 0; m < 4; ++m) {
#pragma unroll
        for (int r = 0; r < 4; ++r) {
            int gi = tI + wr * 64 + m * 16 + ro + r;
            float rs = 0.f, inv = 0.f;
            if (MODE == 5) inv = 1.0f / rowsum[z * 1024 + gi];
#pragma unroll
            for (int n = 0; n < 4; ++n) {
                int gj = tJ + wc * 64 + n * 16 + co;
                float v = acc[m][n][r];
                if (MODE == 0) {
                    v += bias[gj];
                    if (gj < 1024)
                        ((f16*)Cout)[(size_t)z * sC + (size_t)gi * ldC + gj] = (f16)v;
                    else
                        aux[(size_t)z * 524288 + (size_t)(gj - 1024) * 1024 + gi] = (f16)v;
                } else if (MODE == 2) {
                    float e = __expf(fminf(v * scale, 14.f) - 4.f);
                    // e-slot: f16 in the upper 2KB of attn row gi's 4KB slot
                    ((f16*)Cout)[((size_t)z * 1024 + gi) * 2048 + 1024 + gj] = (f16)e;
                    rs += e;
                } else if (MODE == 3) {
                    ((float*)Cout)[(size_t)z * sC + (size_t)gi * ldC + gj] =
                        v + bias[gi] + resid[(size_t)z * sR + (size_t)gi * ldC + gj];
                } else {  // MODE 5
                    ((f16*)Cout)[(size_t)z * sC + (size_t)gi * ldC + gj] = (f16)(v * inv);
                }
            }
            if (MODE == 2) {
                rs += __shfl_xor(rs, 1, 16);
                rs += __shfl_xor(rs, 2, 16);
                rs += __shfl_xor(rs, 4, 16);
                rs += __shfl_xor(rs, 8, 16);
                if ((lane & 15) == 0) atomicAdd(&rowsum[z * 1024 + gi], rs);
            }
        }
    }
}

// ---------------- finalize: attn[row][:] f32 = e16[row][:] * inv_l, in place ----------------
// e-f16 lives in the upper 2KB of each row's 4KB slot; read-all, sync, write-all => self-contained.
__global__ __launch_bounds__(256)
void finalize_attn(float* __restrict__ attn, const float* __restrict__ rowsum) {
    size_t row = blockIdx.x;
    float inv = 1.0f / rowsum[row];
    float* prow = attn + row * 1024;
    half4_t h = *(const half4_t*)((const f16*)prow + 1024 + threadIdx.x * 4);
    __syncthreads();
    float4 o = {(float)h[0] * inv, (float)h[1] * inv, (float)h[2] * inv, (float)h[3] * inv};
    ((float4*)prow)[threadIdx.x] = o;
}

extern "C" void kernel_launch(void* const* d_in, const int* in_sizes, int n_in,
                              void* d_out, int out_size, void* d_ws, size_t ws_size,
                              hipStream_t stream) {
    const float* x  = (const float*)d_in[0];
    const float* Wq = (const float*)d_in[1];
    const float* bq = (const float*)d_in[2];
    const float* Wk = (const float*)d_in[3];
    const float* bk = (const float*)d_in[4];
    const float* Wv = (const float*)d_in[5];
    const float* bv = (const float*)d_in[6];
    const float* Wo = (const float*)d_in[7];
    const float* bo = (const float*)d_in[8];

    float* out0 = (float*)d_out;                           // [16][512][1024]
    float* attn = (float*)d_out + (size_t)NB * DM * NTOK;  // [16][1024][1024] f32 (+e16 slots)

    // workspace layout (f16 units), peak 34,376,704 units = 68.75 MB (proven budget)
    f16* ws    = (f16*)d_ws;
    f16* xt    = ws;                        // [B][N][512]   8,388,608 (dead after QKV)
    f16* oh    = ws;                        // [B][N][512]   alias of xt
    f16* qk    = ws + 8388608;              // [B][N][1024] 16,777,216 (q cols 0..511, k cols 512..1023)
    f16* vh    = ws + 25165824;             // [B][512][N]   8,388,608
    f16* wqkvh = ws + 33554432;             // [1536][512]     786,432
    f16* woh   = ws + 33554432;             // [512][512]    alias of wqkvh
    float* bqkv   = (float*)(ws + 34340864);  // [1536] f32
    float* rowsum = (float*)(ws + 34343936);  // [16384] f32

    const long sTok   = (long)NTOK * DM;      // 524288
    const long sQK    = (long)NTOK * 1024;    // 1048576
    const long sEslot = (long)NTOK * 2048;    // 2097152 (f16 units per batch of e-slot rows)
    const float scal = 0.044194173824159216f;  // 1/sqrt(512)

    hipMemsetAsync(rowsum, 0, 16384 * sizeof(float), stream);
    transpose_x_kernel<<<dim3(32, 16, NB), dim3(32, 8), 0, stream>>>(x, xt);
    convert_wqkv_kernel<<<3072, 256, 0, stream>>>(Wq, Wk, Wv, bq, bk, bv, wqkvh, bqkv);

    // fused QKV: q,k -> qk[b][tok][0..1023]; V -> vh[b][chan][tok] (transposed in epilogue)
    gemm_nt<0, 512><<<dim3(12, 8, NB), 256, 0, stream>>>(xt, wqkvh, qk, bqkv, nullptr,
        vh, nullptr, 512, 512, 1024, sTok, 0, sQK, 0, 0.f);

    // Wo convert AFTER QKV GEMM (woh aliases wqkvh)
    convert_w_kernel<<<1024, 256, 0, stream>>>(Wo, woh, 262144);

    // scores: e = exp(min(s*scal,14)-4) -> f16 e-slots in d_out attn region + rowsum atomics
    gemm_nt<2, 512><<<dim3(8, 8, NB), 256, 0, stream>>>(qk, qk + 512, attn, nullptr, nullptr,
        nullptr, rowsum, 1024, 1024, 0, sQK, sQK, 0, 0, scal);

    // PV: O = (e·V^T)·inv_l -> oh [B][N][512] f16   (MUST run before finalize destroys e-slots)
    gemm_nt<5, 1024><<<dim3(4, 8, NB), 256, 0, stream>>>((const f16*)attn + 1024, vh, oh,
        nullptr, nullptr, nullptr, rowsum, 2048, 1024, 512, sEslot, sTok, sTok, 0, 0.f);

    // finalize: expand e16 -> normalized f32 attn, in place
    finalize_attn<<<NB * NTOK, 256, 0, stream>>>(attn, rowsum);

    // out0 = Wo·O^T + bo + x
    gemm_nt<3, 512><<<dim3(8, 4, NB), 256, 0, stream>>>(woh, oh, out0, bo, x,
        nullptr, nullptr, 512, 512, 1024, 0, sTok, sTok, sTok, 0.f);
}

// Round 4
// 184.561 us; speedup vs baseline: 1.0597x; 1.0597x over previous
//
#include <hip/hip_runtime.h>
#include <hip/hip_bf16.h>

#define DM 512
#define NTOK 1024
#define NB 16

typedef _Float16 f16;
typedef _Float16 half8 __attribute__((ext_vector_type(8)));
typedef _Float16 half4_t __attribute__((ext_vector_type(4)));
typedef float f32x4 __attribute__((ext_vector_type(4)));

__device__ __forceinline__ void gload16(const void* g, void* l) {
    __builtin_amdgcn_global_load_lds(
        (const __attribute__((address_space(1))) void*)g,
        (__attribute__((address_space(3))) void*)l, 16, 0, 0);
}

// ---------------- transpose + convert: x f32 [B][C][N] -> xt f16 [B][N][C] ----------------
__global__ __launch_bounds__(256)
void transpose_x_kernel(const float* __restrict__ x, f16* __restrict__ xt) {
    __shared__ float tile[32][33];
    int b = blockIdx.z;
    int n0 = blockIdx.x * 32, c0 = blockIdx.y * 32;
    int tx = threadIdx.x, ty = threadIdx.y;  // 32 x 8
    const float* xb = x + (size_t)b * DM * NTOK;
#pragma unroll
    for (int i = 0; i < 32; i += 8)
        tile[ty + i][tx] = xb[(size_t)(c0 + ty + i) * NTOK + n0 + tx];
    __syncthreads();
    f16* xtb = xt + (size_t)b * NTOK * DM;
#pragma unroll
    for (int i = 0; i < 32; i += 8)
        xtb[(size_t)(n0 + ty + i) * DM + c0 + tx] = (f16)tile[tx][ty + i];
}

// concat-convert Wq,Wk,Wv -> wqkvh [1536][512] f16, plus bias concat -> bqkv f32[1536]
__global__ __launch_bounds__(256)
void convert_wqkv_kernel(const float* __restrict__ Wq, const float* __restrict__ Wk,
                         const float* __restrict__ Wv, const float* __restrict__ bq,
                         const float* __restrict__ bk, const float* __restrict__ bv,
                         f16* __restrict__ dst, float* __restrict__ bdst) {
    int i = blockIdx.x * 256 + threadIdx.x;  // 0..786431
    int row = i >> 9, col = i & 511;
    float v = (row < 512) ? Wq[i] : (row < 1024) ? Wk[(row - 512) * 512 + col]
                                                 : Wv[(row - 1024) * 512 + col];
    dst[i] = (f16)v;
    if (i < 1536)
        bdst[i] = (i < 512) ? bq[i] : (i < 1024) ? bk[i - 512] : bv[i - 1024];
}

__global__ __launch_bounds__(256)
void convert_w_kernel(const float* __restrict__ src, f16* __restrict__ dst, int n) {
    int i = blockIdx.x * 256 + threadIdx.x;
    if (i < n) dst[i] = (f16)src[i];
}

// vtok [B][N][512] token-major -> vh [B][512][N] channel-major (LDS tile, coalesced both sides)
__global__ __launch_bounds__(256)
void transpose_v_kernel(const f16* __restrict__ vtok, f16* __restrict__ vh) {
    __shared__ f16 tile[32][34];
    int b = blockIdx.z;
    int n0 = blockIdx.x * 32, c0 = blockIdx.y * 32;
    int tx = threadIdx.x, ty = threadIdx.y;  // 32 x 8
    const f16* src = vtok + (size_t)b * NTOK * DM;
#pragma unroll
    for (int i = 0; i < 32; i += 8)
        tile[ty + i][tx] = src[(size_t)(n0 + ty + i) * DM + c0 + tx];  // tile[n][c]
    __syncthreads();
    f16* dst = vh + (size_t)b * DM * NTOK;
#pragma unroll
    for (int i = 0; i < 32; i += 8)
        dst[(size_t)(c0 + ty + i) * NTOK + n0 + tx] = tile[tx][ty + i];
}

// ---------------- NT GEMM: D[i][j] = sum_k A[i][k]*B[j][k], 128x128 tile, 4 waves ----------------
// MODE 0: QKV — gj<1024: f16 qk[z][gi][gj]=D+bias[gj]; gj>=1024: f16 vtok[z][gi][gj-1024]=D+bias[gj]
// MODE 2: scores — e=exp(min(D*scale,14)-4), f16 into e-slot (upper 2KB of attn row slots),
//         plus rowsum atomics (16-lane shuffle reduce first)
// MODE 3: f32 out = D + bias[gi] + resid
// MODE 5: PV — f16 out = D * (1/rowsum[gi])
template<int MODE, int KC>
__global__ __launch_bounds__(256)
void gemm_nt(const f16* __restrict__ A, const f16* __restrict__ B, void* __restrict__ Cout,
             const float* __restrict__ bias, const float* __restrict__ resid,
             f16* __restrict__ aux, float* __restrict__ rowsum,
             int ldA, int ldB, int ldC,
             long sA, long sB, long sC, long sR, float scale) {
    __shared__ f16 As[128 * 32];
    __shared__ f16 Bs[128 * 32];
    int z = blockIdx.z;
    const f16* Ab = A + (size_t)z * sA;
    const f16* Bb = B + (size_t)z * sB;
    int tid = threadIdx.x;
    int wave = tid >> 6, lane = tid & 63;
    int wr = wave >> 1, wc = wave & 1;
    int tI = blockIdx.y * 128, tJ = blockIdx.x * 128;

    f32x4 acc[4][4];
#pragma unroll
    for (int m = 0; m < 4; ++m)
#pragma unroll
        for (int n = 0; n < 4; ++n) acc[m][n] = (f32x4){0.f, 0.f, 0.f, 0.f};

    int frow = lane & 15, fk = (lane >> 4) * 8;   // fragment addressing
    int sr = lane >> 2, sc = (lane & 3) * 8;      // staging addressing

    for (int k0 = 0; k0 < KC; k0 += 32) {
#pragma unroll
        for (int h = 0; h < 2; ++h) {
            int chunk = wave * 2 + h;             // 0..7, 16 rows each
            int r = chunk * 16 + sr;
            const f16* ga = Ab + (size_t)(tI + r) * ldA + k0 + sc;
            const f16* gb = Bb + (size_t)(tJ + r) * ldB + k0 + sc;
            gload16(ga, &As[chunk * 512 + lane * 8]);
            gload16(gb, &Bs[chunk * 512 + lane * 8]);
        }
        asm volatile("s_waitcnt vmcnt(0)" ::: "memory");
        __syncthreads();

        half8 af[4], bf[4];
#pragma unroll
        for (int m = 0; m < 4; ++m)
            af[m] = *(const half8*)&As[(wr * 64 + m * 16 + frow) * 32 + fk];
#pragma unroll
        for (int n = 0; n < 4; ++n)
            bf[n] = *(const half8*)&Bs[(wc * 64 + n * 16 + frow) * 32 + fk];
#pragma unroll
        for (int m = 0; m < 4; ++m)
#pragma unroll
            for (int n = 0; n < 4; ++n)
                acc[m][n] = __builtin_amdgcn_mfma_f32_16x16x32_f16(af[m], bf[n], acc[m][n], 0, 0, 0);
        __syncthreads();
    }

    // epilogue: D row = (lane>>4)*4 + r, col = lane&15  (verified m89 mapping)
    int ro = (lane >> 4) * 4, co = lane & 15;
#pragma unroll
    for (int m = 0; m < 4; ++m) {
#pragma unroll
        for (int r = 0; r < 4; ++r) {
            int gi = tI + wr * 64 + m * 16 + ro + r;
            float rs = 0.f, inv = 0.f;
            if (MODE == 5) inv = 1.0f / rowsum[z * 1024 + gi];
#pragma unroll
            for (int n = 0; n < 4; ++n) {
                int gj = tJ + wc * 64 + n * 16 + co;
                float v = acc[m][n][r];
                if (MODE == 0) {
                    v += bias[gj];
                    if (gj < 1024)   // block-uniform branch (tile never straddles 1024)
                        ((f16*)Cout)[(size_t)z * sC + (size_t)gi * ldC + gj] = (f16)v;
                    else             // V token-major, coalesced
                        aux[(size_t)z * 524288 + (size_t)gi * 512 + (gj - 1024)] = (f16)v;
                } else if (MODE == 2) {
                    float e = __expf(fminf(v * scale, 14.f) - 4.f);
                    // e-slot: f16 in the upper 2KB of attn row gi's 4KB slot
                    ((f16*)Cout)[((size_t)z * 1024 + gi) * 2048 + 1024 + gj] = (f16)e;
                    rs += e;
                } else if (MODE == 3) {
                    ((float*)Cout)[(size_t)z * sC + (size_t)gi * ldC + gj] =
                        v + bias[gi] + resid[(size_t)z * sR + (size_t)gi * ldC + gj];
                } else {  // MODE 5
                    ((f16*)Cout)[(size_t)z * sC + (size_t)gi * ldC + gj] = (f16)(v * inv);
                }
            }
            if (MODE == 2) {
                rs += __shfl_xor(rs, 1, 16);
                rs += __shfl_xor(rs, 2, 16);
                rs += __shfl_xor(rs, 4, 16);
                rs += __shfl_xor(rs, 8, 16);
                if ((lane & 15) == 0) atomicAdd(&rowsum[z * 1024 + gi], rs);
            }
        }
    }
}

// ---------------- finalize: attn[row][:] f32 = e16[row][:] * inv_l, in place ----------------
__global__ __launch_bounds__(256)
void finalize_attn(float* __restrict__ attn, const float* __restrict__ rowsum) {
    size_t row = blockIdx.x;
    float inv = 1.0f / rowsum[row];
    float* prow = attn + row * 1024;
    half4_t h = *(const half4_t*)((const f16*)prow + 1024 + threadIdx.x * 4);
    __syncthreads();
    float4 o = {(float)h[0] * inv, (float)h[1] * inv, (float)h[2] * inv, (float)h[3] * inv};
    ((float4*)prow)[threadIdx.x] = o;
}

extern "C" void kernel_launch(void* const* d_in, const int* in_sizes, int n_in,
                              void* d_out, int out_size, void* d_ws, size_t ws_size,
                              hipStream_t stream) {
    const float* x  = (const float*)d_in[0];
    const float* Wq = (const float*)d_in[1];
    const float* bq = (const float*)d_in[2];
    const float* Wk = (const float*)d_in[3];
    const float* bk = (const float*)d_in[4];
    const float* Wv = (const float*)d_in[5];
    const float* bv = (const float*)d_in[6];
    const float* Wo = (const float*)d_in[7];
    const float* bo = (const float*)d_in[8];

    float* out0 = (float*)d_out;                           // [16][512][1024]
    float* attn = (float*)d_out + (size_t)NB * DM * NTOK;  // [16][1024][1024] f32 (+e16 slots)

    // workspace layout (f16 units), peak 34,376,704 units = 68.75 MB (proven budget)
    f16* ws    = (f16*)d_ws;
    f16* xt    = ws;                        // [B][N][512]   8,388,608 (dead after QKV)
    f16* oh    = ws;                        // [B][N][512]   alias of xt
    f16* qk    = ws + 8388608;              // [B][N][1024] 16,777,216 (q cols 0..511, k cols 512..1023)
    f16* vh    = ws + 25165824;             // [B][512][N]   8,388,608
    f16* wqkvh = ws + 33554432;             // [1536][512]     786,432
    f16* woh   = ws + 33554432;             // [512][512]    alias of wqkvh
    float* bqkv   = (float*)(ws + 34340864);  // [1536] f32
    float* rowsum = (float*)(ws + 34343936);  // [16384] f32

    // vtok lives in the out0 region of d_out (dead until the final GEMM; consumed by transpose_v)
    f16* vtok = (f16*)out0;                 // [B][N][512] f16 = 16 MB of out0's 64 MB

    const long sTok   = (long)NTOK * DM;      // 524288
    const long sQK    = (long)NTOK * 1024;    // 1048576
    const long sEslot = (long)NTOK * 2048;    // 2097152 (f16 units per batch of e-slot rows)
    const float scal = 0.044194173824159216f;  // 1/sqrt(512)

    hipMemsetAsync(rowsum, 0, 16384 * sizeof(float), stream);
    transpose_x_kernel<<<dim3(32, 16, NB), dim3(32, 8), 0, stream>>>(x, xt);
    convert_wqkv_kernel<<<3072, 256, 0, stream>>>(Wq, Wk, Wv, bq, bk, bv, wqkvh, bqkv);

    // fused QKV: q,k -> qk[b][tok][0..1023]; V -> vtok[b][tok][0..511] (all coalesced)
    gemm_nt<0, 512><<<dim3(12, 8, NB), 256, 0, stream>>>(xt, wqkvh, qk, bqkv, nullptr,
        vtok, nullptr, 512, 512, 1024, sTok, 0, sQK, 0, 0.f);

    // Wo convert AFTER QKV GEMM (woh aliases wqkvh)
    convert_w_kernel<<<1024, 256, 0, stream>>>(Wo, woh, 262144);
    // vtok -> vh channel-major (must precede out-proj which overwrites out0)
    transpose_v_kernel<<<dim3(32, 16, NB), dim3(32, 8), 0, stream>>>(vtok, vh);

    // scores: e = exp(min(s*scal,14)-4) -> f16 e-slots in d_out attn region + rowsum atomics
    gemm_nt<2, 512><<<dim3(8, 8, NB), 256, 0, stream>>>(qk, qk + 512, attn, nullptr, nullptr,
        nullptr, rowsum, 1024, 1024, 0, sQK, sQK, 0, 0, scal);

    // PV: O = (e·V^T)·inv_l -> oh [B][N][512] f16   (MUST run before finalize destroys e-slots)
    gemm_nt<5, 1024><<<dim3(4, 8, NB), 256, 0, stream>>>((const f16*)attn + 1024, vh, oh,
        nullptr, nullptr, nullptr, rowsum, 2048, 1024, 512, sEslot, sTok, sTok, 0, 0.f);

    // finalize: expand e16 -> normalized f32 attn, in place
    finalize_attn<<<NB * NTOK, 256, 0, stream>>>(attn, rowsum);

    // out0 = Wo·O^T + bo + x
    gemm_nt<3, 512><<<dim3(8, 4, NB), 256, 0, stream>>>(woh, oh, out0, bo, x,
        nullptr, nullptr, 512, 512, 1024, 0, sTok, sTok, sTok, 0.f);
}